// Round 17
// baseline (111.477 us; speedup 1.0000x reference)
//
#include <hip/hip_runtime.h>

#define BB 1024
#define TT 512
#define KK 64
#define CH 8   // scan steps per chunk

typedef float f32x4 __attribute__((ext_vector_type(4)));
typedef float f32x2 __attribute__((ext_vector_type(2)));

__device__ __forceinline__ float wave_sum(float v) {
#pragma unroll
    for (int off = 1; off < 64; off <<= 1) v += __shfl_xor(v, off);
    return v;
}

__device__ __forceinline__ float wave_max(float v) {
#pragma unroll
    for (int off = 1; off < 64; off <<= 1) v = fmaxf(v, __shfl_xor(v, off));
    return v;
}

#if __has_builtin(__builtin_amdgcn_mov_dpp)
__device__ __forceinline__ float dpp_xor1_f(float x) {
    return __uint_as_float((unsigned)__builtin_amdgcn_mov_dpp(
        (int)__float_as_uint(x), 0xB1, 0xF, 0xF, true));  // quad [1,0,3,2]
}
__device__ __forceinline__ float dpp_xor2_f(float x) {
    return __uint_as_float((unsigned)__builtin_amdgcn_mov_dpp(
        (int)__float_as_uint(x), 0x4E, 0xF, 0xF, true));  // quad [2,3,0,1]
}
#else
__device__ __forceinline__ float dpp_xor1_f(float x) { return __shfl_xor(x, 1); }
__device__ __forceinline__ float dpp_xor2_f(float x) { return __shfl_xor(x, 2); }
#endif

// One wave per batch element; lane j owns state j (r16 structure, comms
// upgraded). p[j] lives in a REGISTER (pcur, lane j). Per-step slice gather
// is 16 ds_bpermute_b32 (single LDS-pipe hop, reg->reg) instead of r16's
// ds_write + 4 ds_read (two serialized LDS latencies ~240cy -> one ~120cy).
// Then 32 v_pk_fma_f32 (4 permuted quad rows x 16k, 4-deep chains) ->
// DPP quad reduce-scatter (zero cndmasks) -> *el -> pcur. Renorm pow-2
// exact, per CHUNK, off-chain: exponent of readfirstlane(pcur) folded into
// el0. Zero LDS in the loop.
__global__ void __launch_bounds__(64)
__attribute__((amdgpu_waves_per_eu(1, 1)))
crf_fwd(
    const float* __restrict__ logits,
    const float* __restrict__ trans,
    const int* __restrict__ gold,
    const int* __restrict__ seq_len,
    float* __restrict__ ws)
{
    const int b = blockIdx.x;
    const int j = threadIdx.x & 63;
    const int qr = (j >> 2) << 2;    // quad base row
    const int c = j & 3;             // quad position = k-slice index
    const int sc = c << 4;           // slice col base (16 states)
    const int vb = sc << 2;          // bpermute byte base (lane*4)
    const float* lg = logits + (size_t)b * (TT * KK);
    const int* gd = gold + (size_t)b * TT;
    const int L = seq_len[b];

    // ---- Phase A: lane-parallel first & second terms (off the scan) ----
    float af = 0.0f, asec = 0.0f;
#pragma unroll
    for (int q = 0; q < TT / 64; ++q) {
        int t = q * 64 + j;
        if (t < L) {
            int g0 = gd[t];
            af += lg[t * KK + g0];
            if (t + 1 < L) {
                int g1 = gd[t + 1];
                asec += trans[g0 * KK + g1];
            }
        }
    }

    // ---- E fragment: 4 rows (PERMUTED order qr+(c^rr)) x my 16-k slice,
    //      exp()'d into 32 named f32x2 regs (Erq covers k = sc+2q..2q+1) ----
    f32x2 E00, E01, E02, E03, E04, E05, E06, E07;
    f32x2 E10, E11, E12, E13, E14, E15, E16, E17;
    f32x2 E20, E21, E22, E23, E24, E25, E26, E27;
    f32x2 E30, E31, E32, E33, E34, E35, E36, E37;
#define LDROW(RR, N0, N1, N2, N3, N4, N5, N6, N7) { \
    const float* rp_ = trans + (size_t)(qr + (c ^ (RR))) * KK + sc; \
    f32x4 v0 = *(const f32x4*)(rp_ + 0);  f32x4 v1 = *(const f32x4*)(rp_ + 4); \
    f32x4 v2 = *(const f32x4*)(rp_ + 8);  f32x4 v3 = *(const f32x4*)(rp_ + 12); \
    N0.x = __expf(v0.x); N0.y = __expf(v0.y); N1.x = __expf(v0.z); N1.y = __expf(v0.w); \
    N2.x = __expf(v1.x); N2.y = __expf(v1.y); N3.x = __expf(v1.z); N3.y = __expf(v1.w); \
    N4.x = __expf(v2.x); N4.y = __expf(v2.y); N5.x = __expf(v2.z); N5.y = __expf(v2.w); \
    N6.x = __expf(v3.x); N6.y = __expf(v3.y); N7.x = __expf(v3.z); N7.y = __expf(v3.w); }
    LDROW(0, E00, E01, E02, E03, E04, E05, E06, E07)
    LDROW(1, E10, E11, E12, E13, E14, E15, E16, E17)
    LDROW(2, E20, E21, E22, E23, E24, E25, E26, E27)
    LDROW(3, E30, E31, E32, E33, E34, E35, E36, E37)
#undef LDROW

    // ---- t = 0 init: lane j holds p[j] in a register ----
    float a0 = lg[j];
    float mx = wave_max(a0);
    float pcur = __expf(a0 - mx);    // in (0, 1]
    int Etot = 0;

    // ---- preload chunk 0 (t = 1..8) ----
    f32x4 nl0, nl1;
    nl0.x = lg[1 * KK + j]; nl0.y = lg[2 * KK + j];
    nl0.z = lg[3 * KK + j]; nl0.w = lg[4 * KK + j];
    nl1.x = lg[5 * KK + j]; nl1.y = lg[6 * KK + j];
    nl1.z = lg[7 * KK + j]; nl1.w = lg[8 * KK + j];

#define PK(EH, W, A) A = __builtin_elementwise_fma(EH, (W), A);
#define PM(EH, W) ((EH) * (W))

    // One step: 16 bpermute (slice gather, 1 hop) -> 32 pk_fma (4-deep) ->
    // permuted-row quad reduce -> *el -> pcur.
#define STEP(EL) { \
    int src_ = (int)__float_as_uint(pcur); \
    int g0_  = __builtin_amdgcn_ds_bpermute(vb + 0,  src_); \
    int g1_  = __builtin_amdgcn_ds_bpermute(vb + 4,  src_); \
    int g2_  = __builtin_amdgcn_ds_bpermute(vb + 8,  src_); \
    int g3_  = __builtin_amdgcn_ds_bpermute(vb + 12, src_); \
    int g4_  = __builtin_amdgcn_ds_bpermute(vb + 16, src_); \
    int g5_  = __builtin_amdgcn_ds_bpermute(vb + 20, src_); \
    int g6_  = __builtin_amdgcn_ds_bpermute(vb + 24, src_); \
    int g7_  = __builtin_amdgcn_ds_bpermute(vb + 28, src_); \
    int g8_  = __builtin_amdgcn_ds_bpermute(vb + 32, src_); \
    int g9_  = __builtin_amdgcn_ds_bpermute(vb + 36, src_); \
    int g10_ = __builtin_amdgcn_ds_bpermute(vb + 40, src_); \
    int g11_ = __builtin_amdgcn_ds_bpermute(vb + 44, src_); \
    int g12_ = __builtin_amdgcn_ds_bpermute(vb + 48, src_); \
    int g13_ = __builtin_amdgcn_ds_bpermute(vb + 52, src_); \
    int g14_ = __builtin_amdgcn_ds_bpermute(vb + 56, src_); \
    int g15_ = __builtin_amdgcn_ds_bpermute(vb + 60, src_); \
    f32x2 W0_, W1_, W2_, W3_, W4_, W5_, W6_, W7_; \
    W0_.x = __uint_as_float((unsigned)g0_);  W0_.y = __uint_as_float((unsigned)g1_); \
    W1_.x = __uint_as_float((unsigned)g2_);  W1_.y = __uint_as_float((unsigned)g3_); \
    W2_.x = __uint_as_float((unsigned)g4_);  W2_.y = __uint_as_float((unsigned)g5_); \
    W3_.x = __uint_as_float((unsigned)g6_);  W3_.y = __uint_as_float((unsigned)g7_); \
    W4_.x = __uint_as_float((unsigned)g8_);  W4_.y = __uint_as_float((unsigned)g9_); \
    W5_.x = __uint_as_float((unsigned)g10_); W5_.y = __uint_as_float((unsigned)g11_); \
    W6_.x = __uint_as_float((unsigned)g12_); W6_.y = __uint_as_float((unsigned)g13_); \
    W7_.x = __uint_as_float((unsigned)g14_); W7_.y = __uint_as_float((unsigned)g15_); \
    f32x2 a0_ = PM(E00, W0_), a1_ = PM(E10, W0_), a2_ = PM(E20, W0_), a3_ = PM(E30, W0_); \
    f32x2 b0_ = PM(E04, W4_), b1_ = PM(E14, W4_), b2_ = PM(E24, W4_), b3_ = PM(E34, W4_); \
    PK(E01, W1_, a0_) PK(E11, W1_, a1_) PK(E21, W1_, a2_) PK(E31, W1_, a3_) \
    PK(E05, W5_, b0_) PK(E15, W5_, b1_) PK(E25, W5_, b2_) PK(E35, W5_, b3_) \
    PK(E02, W2_, a0_) PK(E12, W2_, a1_) PK(E22, W2_, a2_) PK(E32, W2_, a3_) \
    PK(E06, W6_, b0_) PK(E16, W6_, b1_) PK(E26, W6_, b2_) PK(E36, W6_, b3_) \
    PK(E03, W3_, a0_) PK(E13, W3_, a1_) PK(E23, W3_, a2_) PK(E33, W3_, a3_) \
    PK(E07, W7_, b0_) PK(E17, W7_, b1_) PK(E27, W7_, b2_) PK(E37, W7_, b3_) \
    f32x2 t0_ = a0_ + b0_, t1_ = a1_ + b1_, t2_ = a2_ + b2_, t3_ = a3_ + b3_; \
    float P0_ = t0_.x + t0_.y; float P1_ = t1_.x + t1_.y; \
    float P2_ = t2_.x + t2_.y; float P3_ = t3_.x + t3_.y; \
    float Q0_ = P0_ + dpp_xor1_f(P1_); \
    float Q1_ = P2_ + dpp_xor1_f(P3_); \
    float s_ = Q0_ + dpp_xor2_f(Q1_);       /* full row-j sum, lane j */ \
    pcur = s_ * (EL); }

    // ---- main loop: full chunks only (all CH steps strictly < L) ----
    int t0 = 1;
    for (; t0 + CH <= L; t0 += CH) {
        // anti-spill anchors for the 32 E regs
        asm volatile("" : "+v"(E00), "+v"(E01), "+v"(E02), "+v"(E03),
                          "+v"(E04), "+v"(E05), "+v"(E06), "+v"(E07),
                          "+v"(E10), "+v"(E11), "+v"(E12), "+v"(E13),
                          "+v"(E14), "+v"(E15), "+v"(E16), "+v"(E17));
        asm volatile("" : "+v"(E20), "+v"(E21), "+v"(E22), "+v"(E23),
                          "+v"(E24), "+v"(E25), "+v"(E26), "+v"(E27),
                          "+v"(E30), "+v"(E31), "+v"(E32), "+v"(E33),
                          "+v"(E34), "+v"(E35), "+v"(E36), "+v"(E37));

        // exp of current chunk's logits (off the critical p-chain)
        f32x4 el0, el1;
        el0.x = __expf(nl0.x); el0.y = __expf(nl0.y);
        el0.z = __expf(nl0.z); el0.w = __expf(nl0.w);
        el1.x = __expf(nl1.x); el1.y = __expf(nl1.y);
        el1.z = __expf(nl1.z); el1.w = __expf(nl1.w);

        // prefetch next chunk
        {
            int tn = t0 + CH;
            int c0 = tn + 0; c0 = (c0 > TT - 1) ? TT - 1 : c0;
            int c1 = tn + 1; c1 = (c1 > TT - 1) ? TT - 1 : c1;
            int c2 = tn + 2; c2 = (c2 > TT - 1) ? TT - 1 : c2;
            int c3 = tn + 3; c3 = (c3 > TT - 1) ? TT - 1 : c3;
            int c4 = tn + 4; c4 = (c4 > TT - 1) ? TT - 1 : c4;
            int c5 = tn + 5; c5 = (c5 > TT - 1) ? TT - 1 : c5;
            int c6 = tn + 6; c6 = (c6 > TT - 1) ? TT - 1 : c6;
            int c7 = tn + 7; c7 = (c7 > TT - 1) ? TT - 1 : c7;
            nl0.x = lg[c0 * KK + j]; nl0.y = lg[c1 * KK + j];
            nl0.z = lg[c2 * KK + j]; nl0.w = lg[c3 * KK + j];
            nl1.x = lg[c4 * KK + j]; nl1.y = lg[c5 * KK + j];
            nl1.z = lg[c6 * KK + j]; nl1.w = lg[c7 * KK + j];
        }

        // chunk-top renorm (off-chain): fold 2^-exponent(p[0]) into el0
        {
            float p00 = __uint_as_float(
                (unsigned)__builtin_amdgcn_readfirstlane((int)__float_as_uint(pcur)));
            unsigned pb = __float_as_uint(p00);
            int ee = (int)((pb >> 23) & 255u) - 127;
            Etot += ee;
            float scl = __uint_as_float((unsigned)((127 - ee) << 23));
            el0.x *= scl;
        }

        STEP(el0.x) STEP(el0.y) STEP(el0.z) STEP(el0.w)
        STEP(el1.x) STEP(el1.y) STEP(el1.z) STEP(el1.w)
    }

    // ---- remainder: at most CH-1 steps, wave-uniform guards ----
    if (t0 < L) {
        f32x4 el0, el1;
        el0.x = __expf(nl0.x); el0.y = __expf(nl0.y);
        el0.z = __expf(nl0.z); el0.w = __expf(nl0.w);
        el1.x = __expf(nl1.x); el1.y = __expf(nl1.y);
        el1.z = __expf(nl1.z); el1.w = __expf(nl1.w);
        {
            float p00 = __uint_as_float(
                (unsigned)__builtin_amdgcn_readfirstlane((int)__float_as_uint(pcur)));
            unsigned pb = __float_as_uint(p00);
            int ee = (int)((pb >> 23) & 255u) - 127;
            Etot += ee;
            float scl = __uint_as_float((unsigned)((127 - ee) << 23));
            el0.x *= scl;
        }
        if (t0 + 0 < L) { STEP(el0.x) }
        if (t0 + 1 < L) { STEP(el0.y) }
        if (t0 + 2 < L) { STEP(el0.z) }
        if (t0 + 3 < L) { STEP(el0.w) }
        if (t0 + 4 < L) { STEP(el1.x) }
        if (t0 + 5 < L) { STEP(el1.y) }
        if (t0 + 6 < L) { STEP(el1.z) }
    }
#undef STEP
#undef PK
#undef PM

    float sump = wave_sum(pcur);
    float third_b = mx + (float)Etot * 0.6931471805599453f + __logf(sump);
    float first_b = wave_sum(af);
    float second_b = wave_sum(asec);

    if (j == 0) {
        ws[b] = (third_b - first_b - second_b) * (1.0f / (float)BB);
    }
}

// Deterministic fixed-order reduction of the 1024 per-b contributions.
__global__ void crf_reduce(const float* __restrict__ ws, float* __restrict__ out) {
    int tid = threadIdx.x;  // 256 threads
    float v = ws[tid] + ws[tid + 256] + ws[tid + 512] + ws[tid + 768];
    v = wave_sum(v);
    __shared__ float sm[4];
    if ((tid & 63) == 0) sm[tid >> 6] = v;
    __syncthreads();
    if (tid == 0) out[0] = (sm[0] + sm[1]) + (sm[2] + sm[3]);
}

extern "C" void kernel_launch(void* const* d_in, const int* in_sizes, int n_in,
                              void* d_out, int out_size, void* d_ws, size_t ws_size,
                              hipStream_t stream) {
    const float* logits = (const float*)d_in[0];
    const float* trans  = (const float*)d_in[1];
    const int*   gold   = (const int*)d_in[2];
    const int*   slen   = (const int*)d_in[3];
    float* out = (float*)d_out;
    float* ws = (float*)d_ws;

    hipLaunchKernelGGL(crf_fwd, dim3(BB), dim3(64), 0, stream,
                       logits, trans, gold, slen, ws);
    hipLaunchKernelGGL(crf_reduce, dim3(1), dim3(256), 0, stream, ws, out);
}

// Round 18
// 87.569 us; speedup vs baseline: 1.2730x; 1.2730x over previous
//
#include <hip/hip_runtime.h>

#define BB 1024
#define TT 512
#define KK 64
#define CH 8   // scan steps per chunk

typedef float f32x4 __attribute__((ext_vector_type(4)));
typedef float f32x2 __attribute__((ext_vector_type(2)));

#define LO2(v4) __builtin_shufflevector((v4), (v4), 0, 1)
#define HI2(v4) __builtin_shufflevector((v4), (v4), 2, 3)

__device__ __forceinline__ float wave_sum(float v) {
#pragma unroll
    for (int off = 1; off < 64; off <<= 1) v += __shfl_xor(v, off);
    return v;
}

__device__ __forceinline__ float wave_max(float v) {
#pragma unroll
    for (int off = 1; off < 64; off <<= 1) v = fmaxf(v, __shfl_xor(v, off));
    return v;
}

#if __has_builtin(__builtin_amdgcn_mov_dpp)
__device__ __forceinline__ float dpp_xor1_f(float x) {
    return __uint_as_float((unsigned)__builtin_amdgcn_mov_dpp(
        (int)__float_as_uint(x), 0xB1, 0xF, 0xF, true));  // quad [1,0,3,2]
}
__device__ __forceinline__ float dpp_xor2_f(float x) {
    return __uint_as_float((unsigned)__builtin_amdgcn_mov_dpp(
        (int)__float_as_uint(x), 0x4E, 0xF, 0xF, true));  // quad [2,3,0,1]
}
#else
__device__ __forceinline__ float dpp_xor1_f(float x) { return __shfl_xor(x, 1); }
__device__ __forceinline__ float dpp_xor2_f(float x) { return __shfl_xor(x, 2); }
#endif

// One wave per batch element; lane j owns state j. r16 structure (best
// verified: LDS f32 single-buffer, 1 ds_write + 4 ds_read_b128 per step —
// r17 showed 16 bpermutes regress via DS-pipe op count; r14 MFMA and r15
// multi-wave also regressed). This round: 8 accumulators (4-deep pk chains)
// and renorm hoisted ahead of the chunk-top blob. Per step: 4 ds_read_b128
// (quad lane c's 16-k slice) -> 32 v_pk_fma_f32 over 4 PERMUTED rows
// (qr+(c^rr)) -> DPP quad reduce-scatter (zero cndmasks) -> *el -> ds_write.
// Renorm pow-2 exact, per CHUNK, off-chain: exponent of p[0] folded into el0.
__global__ void __launch_bounds__(64)
__attribute__((amdgpu_waves_per_eu(1, 1)))
crf_fwd(
    const float* __restrict__ logits,
    const float* __restrict__ trans,
    const int* __restrict__ gold,
    const int* __restrict__ seq_len,
    float* __restrict__ ws)
{
    __shared__ __align__(16) float buf[KK];   // p state (f32)
    const int b = blockIdx.x;
    const int j = threadIdx.x & 63;
    const int qr = (j >> 2) << 2;    // quad base row
    const int c = j & 3;             // quad position = k-slice index
    const int sc = c << 4;           // slice col base (16 states)
    const float* lg = logits + (size_t)b * (TT * KK);
    const int* gd = gold + (size_t)b * TT;
    const int L = seq_len[b];

    // ---- Phase A: lane-parallel first & second terms (off the scan) ----
    float af = 0.0f, asec = 0.0f;
#pragma unroll
    for (int q = 0; q < TT / 64; ++q) {
        int t = q * 64 + j;
        if (t < L) {
            int g0 = gd[t];
            af += lg[t * KK + g0];
            if (t + 1 < L) {
                int g1 = gd[t + 1];
                asec += trans[g0 * KK + g1];
            }
        }
    }

    // ---- E fragment: 4 rows (PERMUTED order qr+(c^rr)) x my 16-k slice,
    //      exp()'d into 32 named f32x2 regs (Erq covers k = sc+2q..2q+1) ----
    f32x2 E00, E01, E02, E03, E04, E05, E06, E07;
    f32x2 E10, E11, E12, E13, E14, E15, E16, E17;
    f32x2 E20, E21, E22, E23, E24, E25, E26, E27;
    f32x2 E30, E31, E32, E33, E34, E35, E36, E37;
#define LDROW(RR, N0, N1, N2, N3, N4, N5, N6, N7) { \
    const float* rp_ = trans + (size_t)(qr + (c ^ (RR))) * KK + sc; \
    f32x4 v0 = *(const f32x4*)(rp_ + 0);  f32x4 v1 = *(const f32x4*)(rp_ + 4); \
    f32x4 v2 = *(const f32x4*)(rp_ + 8);  f32x4 v3 = *(const f32x4*)(rp_ + 12); \
    N0.x = __expf(v0.x); N0.y = __expf(v0.y); N1.x = __expf(v0.z); N1.y = __expf(v0.w); \
    N2.x = __expf(v1.x); N2.y = __expf(v1.y); N3.x = __expf(v1.z); N3.y = __expf(v1.w); \
    N4.x = __expf(v2.x); N4.y = __expf(v2.y); N5.x = __expf(v2.z); N5.y = __expf(v2.w); \
    N6.x = __expf(v3.x); N6.y = __expf(v3.y); N7.x = __expf(v3.z); N7.y = __expf(v3.w); }
    LDROW(0, E00, E01, E02, E03, E04, E05, E06, E07)
    LDROW(1, E10, E11, E12, E13, E14, E15, E16, E17)
    LDROW(2, E20, E21, E22, E23, E24, E25, E26, E27)
    LDROW(3, E30, E31, E32, E33, E34, E35, E36, E37)
#undef LDROW

    // ---- t = 0 init ----
    float a0 = lg[j];
    float mx = wave_max(a0);
    buf[j] = __expf(a0 - mx);       // in (0, 1]
    int Etot = 0;

    // ---- preload chunk 0 (t = 1..8) ----
    f32x4 nl0, nl1;
    nl0.x = lg[1 * KK + j]; nl0.y = lg[2 * KK + j];
    nl0.z = lg[3 * KK + j]; nl0.w = lg[4 * KK + j];
    nl1.x = lg[5 * KK + j]; nl1.y = lg[6 * KK + j];
    nl1.z = lg[7 * KK + j]; nl1.w = lg[8 * KK + j];

#define PK(EH, W, A) A = __builtin_elementwise_fma(EH, (W), A);
#define PM(EH, W) ((EH) * (W))

    // One step: 4 slice reads -> 32 pk_fma in 8 accumulators (4-deep) ->
    // pairwise pk-add merge -> permuted-row quad reduce -> *el -> store.
#define STEP(EL) { \
    const f32x4* bs_ = (const f32x4*)(buf + sc); \
    f32x4 W0_ = bs_[0], W1_ = bs_[1], W2_ = bs_[2], W3_ = bs_[3]; \
    f32x2 a0_ = PM(E00, LO2(W0_)), a1_ = PM(E10, LO2(W0_)); \
    f32x2 a2_ = PM(E20, LO2(W0_)), a3_ = PM(E30, LO2(W0_)); \
    f32x2 b0_ = PM(E04, LO2(W2_)), b1_ = PM(E14, LO2(W2_)); \
    f32x2 b2_ = PM(E24, LO2(W2_)), b3_ = PM(E34, LO2(W2_)); \
    PK(E01, HI2(W0_), a0_) PK(E11, HI2(W0_), a1_) PK(E21, HI2(W0_), a2_) PK(E31, HI2(W0_), a3_) \
    PK(E05, HI2(W2_), b0_) PK(E15, HI2(W2_), b1_) PK(E25, HI2(W2_), b2_) PK(E35, HI2(W2_), b3_) \
    PK(E02, LO2(W1_), a0_) PK(E12, LO2(W1_), a1_) PK(E22, LO2(W1_), a2_) PK(E32, LO2(W1_), a3_) \
    PK(E06, LO2(W3_), b0_) PK(E16, LO2(W3_), b1_) PK(E26, LO2(W3_), b2_) PK(E36, LO2(W3_), b3_) \
    PK(E03, HI2(W1_), a0_) PK(E13, HI2(W1_), a1_) PK(E23, HI2(W1_), a2_) PK(E33, HI2(W1_), a3_) \
    PK(E07, HI2(W3_), b0_) PK(E17, HI2(W3_), b1_) PK(E27, HI2(W3_), b2_) PK(E37, HI2(W3_), b3_) \
    f32x2 t0_ = a0_ + b0_, t1_ = a1_ + b1_, t2_ = a2_ + b2_, t3_ = a3_ + b3_; \
    float P0_ = t0_.x + t0_.y; float P1_ = t1_.x + t1_.y; \
    float P2_ = t2_.x + t2_.y; float P3_ = t3_.x + t3_.y; \
    float Q0_ = P0_ + dpp_xor1_f(P1_); \
    float Q1_ = P2_ + dpp_xor1_f(P3_); \
    float s_ = Q0_ + dpp_xor2_f(Q1_);       /* full row-j sum, lane j */ \
    float pn_ = s_ * (EL); \
    buf[j] = pn_; }

    // ---- main loop: full chunks only (all CH steps strictly < L) ----
    int t0 = 1;
    for (; t0 + CH <= L; t0 += CH) {
        // anti-spill anchors for the 32 E regs
        asm volatile("" : "+v"(E00), "+v"(E01), "+v"(E02), "+v"(E03),
                          "+v"(E04), "+v"(E05), "+v"(E06), "+v"(E07),
                          "+v"(E10), "+v"(E11), "+v"(E12), "+v"(E13),
                          "+v"(E14), "+v"(E15), "+v"(E16), "+v"(E17));
        asm volatile("" : "+v"(E20), "+v"(E21), "+v"(E22), "+v"(E23),
                          "+v"(E24), "+v"(E25), "+v"(E26), "+v"(E27),
                          "+v"(E30), "+v"(E31), "+v"(E32), "+v"(E33),
                          "+v"(E34), "+v"(E35), "+v"(E36), "+v"(E37));

        // chunk-top renorm FIRST (off-chain): 2^-exponent(p[0]) -> el0
        float scl;
        {
            float p00 = buf[0];                       // uniform LDS read
            unsigned pb = __float_as_uint(p00);
            int ee = (int)((pb >> 23) & 255u) - 127;
            Etot += ee;
            scl = __uint_as_float((unsigned)((127 - ee) << 23));
        }

        // exp of current chunk's logits (off the critical p-chain)
        f32x4 el0, el1;
        el0.x = __expf(nl0.x) * scl; el0.y = __expf(nl0.y);
        el0.z = __expf(nl0.z);       el0.w = __expf(nl0.w);
        el1.x = __expf(nl1.x); el1.y = __expf(nl1.y);
        el1.z = __expf(nl1.z); el1.w = __expf(nl1.w);

        // prefetch next chunk
        {
            int tn = t0 + CH;
            int c0 = tn + 0; c0 = (c0 > TT - 1) ? TT - 1 : c0;
            int c1 = tn + 1; c1 = (c1 > TT - 1) ? TT - 1 : c1;
            int c2 = tn + 2; c2 = (c2 > TT - 1) ? TT - 1 : c2;
            int c3 = tn + 3; c3 = (c3 > TT - 1) ? TT - 1 : c3;
            int c4 = tn + 4; c4 = (c4 > TT - 1) ? TT - 1 : c4;
            int c5 = tn + 5; c5 = (c5 > TT - 1) ? TT - 1 : c5;
            int c6 = tn + 6; c6 = (c6 > TT - 1) ? TT - 1 : c6;
            int c7 = tn + 7; c7 = (c7 > TT - 1) ? TT - 1 : c7;
            nl0.x = lg[c0 * KK + j]; nl0.y = lg[c1 * KK + j];
            nl0.z = lg[c2 * KK + j]; nl0.w = lg[c3 * KK + j];
            nl1.x = lg[c4 * KK + j]; nl1.y = lg[c5 * KK + j];
            nl1.z = lg[c6 * KK + j]; nl1.w = lg[c7 * KK + j];
        }

        STEP(el0.x) STEP(el0.y) STEP(el0.z) STEP(el0.w)
        STEP(el1.x) STEP(el1.y) STEP(el1.z) STEP(el1.w)
    }

    // ---- remainder: at most CH-1 steps, wave-uniform guards ----
    if (t0 < L) {
        float scl;
        {
            float p00 = buf[0];
            unsigned pb = __float_as_uint(p00);
            int ee = (int)((pb >> 23) & 255u) - 127;
            Etot += ee;
            scl = __uint_as_float((unsigned)((127 - ee) << 23));
        }
        f32x4 el0, el1;
        el0.x = __expf(nl0.x) * scl; el0.y = __expf(nl0.y);
        el0.z = __expf(nl0.z);       el0.w = __expf(nl0.w);
        el1.x = __expf(nl1.x); el1.y = __expf(nl1.y);
        el1.z = __expf(nl1.z); el1.w = __expf(nl1.w);
        if (t0 + 0 < L) { STEP(el0.x) }
        if (t0 + 1 < L) { STEP(el0.y) }
        if (t0 + 2 < L) { STEP(el0.z) }
        if (t0 + 3 < L) { STEP(el0.w) }
        if (t0 + 4 < L) { STEP(el1.x) }
        if (t0 + 5 < L) { STEP(el1.y) }
        if (t0 + 6 < L) { STEP(el1.z) }
    }
#undef STEP
#undef PK
#undef PM

    float pfin = buf[j];
    float sump = wave_sum(pfin);
    float third_b = mx + (float)Etot * 0.6931471805599453f + __logf(sump);
    float first_b = wave_sum(af);
    float second_b = wave_sum(asec);

    if (j == 0) {
        ws[b] = (third_b - first_b - second_b) * (1.0f / (float)BB);
    }
}

// Deterministic fixed-order reduction of the 1024 per-b contributions.
__global__ void crf_reduce(const float* __restrict__ ws, float* __restrict__ out) {
    int tid = threadIdx.x;  // 256 threads
    float v = ws[tid] + ws[tid + 256] + ws[tid + 512] + ws[tid + 768];
    v = wave_sum(v);
    __shared__ float sm[4];
    if ((tid & 63) == 0) sm[tid >> 6] = v;
    __syncthreads();
    if (tid == 0) out[0] = (sm[0] + sm[1]) + (sm[2] + sm[3]);
}

extern "C" void kernel_launch(void* const* d_in, const int* in_sizes, int n_in,
                              void* d_out, int out_size, void* d_ws, size_t ws_size,
                              hipStream_t stream) {
    const float* logits = (const float*)d_in[0];
    const float* trans  = (const float*)d_in[1];
    const int*   gold   = (const int*)d_in[2];
    const int*   slen   = (const int*)d_in[3];
    float* out = (float*)d_out;
    float* ws = (float*)d_ws;

    hipLaunchKernelGGL(crf_fwd, dim3(BB), dim3(64), 0, stream,
                       logits, trans, gold, slen, ws);
    hipLaunchKernelGGL(crf_reduce, dim3(1), dim3(256), 0, stream, ws, out);
}